// Round 6
// baseline (1774.788 us; speedup 1.0000x reference)
//
#include <hip/hip_runtime.h>

typedef _Float16 f16x8 __attribute__((ext_vector_type(8)));
typedef float f32x4 __attribute__((ext_vector_type(4)));

constexpr int D = 256;
constexpr int NUTT = 64;
constexpr int L = 512;
constexpr int G = 768;           // 3*D

// LDS-only barrier: orders ds_* ops across the workgroup WITHOUT draining
// vmcnt — global prefetch loads / wo stores stay in flight across steps.
__device__ __forceinline__ void lds_barrier() {
  asm volatile("s_waitcnt lgkmcnt(0)\n\ts_barrier" ::: "memory");
}

__device__ __forceinline__ float fast_rcp(float x) {
  return __builtin_amdgcn_rcpf(x);
}
__device__ __forceinline__ float sigm(float x) {
  return fast_rcp(1.0f + __expf(-x));
}
__device__ __forceinline__ float tanh_f(float x) {
  float ax = fabsf(x);
  float e = __expf(-2.0f * ax);
  float r = (1.0f - e) * fast_rcp(1.0f + e);
  return copysignf(r, x);
}

// ---------------------------------------------------------------------------
// Kernel A: split Wih (f32) into f16 hi/lo pair for split-f16 MFMA GEMM.
// ---------------------------------------------------------------------------
__global__ __launch_bounds__(256) void split_wih(
    const float* __restrict__ Wih, _Float16* __restrict__ hi,
    _Float16* __restrict__ lo) {
  const int i = blockIdx.x * 256 + threadIdx.x;    // grid = 768 blocks
  float v = Wih[i];
  _Float16 h = (_Float16)v;
  hi[i] = h;
  lo[i] = (_Float16)(v - (float)h);
}

// ---------------------------------------------------------------------------
// Kernel B: gx[m][g] = embed[tokens[m]][:] . Wih[g][:] + bih[g]
// MFMA split-f16, LDS-free (R5-verified). M=32768, N=768, K=256.
// BM=64 (4 waves x 16 rows), BN=128 (8 16-col tiles).
// ---------------------------------------------------------------------------
__global__ __launch_bounds__(256) void gx_gemm_mfma(
    const int* __restrict__ tokens, const float* __restrict__ embed,
    const _Float16* __restrict__ whi, const _Float16* __restrict__ wlo,
    const float* __restrict__ bih, float* __restrict__ gx) {
  const int tid = threadIdx.x;
  const int m0 = blockIdx.x * 64;
  const int n0 = blockIdx.y * 128;

  const int w = tid >> 6;                // wave 0..3
  const int lane = tid & 63;
  const int l15 = lane & 15;
  const int lk = lane >> 4;

  const int tok = tokens[m0 + 16 * w + l15];
  const float* arow = embed + (size_t)tok * D;

  f32x4 acc[8] = {};
  const _Float16* bh0 = whi + (size_t)(n0 + l15) * D + 8 * lk;
  const _Float16* bl0 = wlo + (size_t)(n0 + l15) * D + 8 * lk;

#pragma unroll
  for (int f = 0; f < 8; ++f) {
    const float* ap = arow + 32 * f + 8 * lk;
    float4 v0 = *(const float4*)(ap);
    float4 v1 = *(const float4*)(ap + 4);
    float av[8] = {v0.x, v0.y, v0.z, v0.w, v1.x, v1.y, v1.z, v1.w};
    f16x8 ahi, alo;
#pragma unroll
    for (int j = 0; j < 8; ++j) {
      _Float16 h = (_Float16)av[j];
      ahi[j] = h;
      alo[j] = (_Float16)(av[j] - (float)h);
    }
#pragma unroll
    for (int i = 0; i < 8; ++i) {
      f16x8 bhi = *(const f16x8*)(bh0 + (size_t)(16 * i) * D + 32 * f);
      f16x8 blo = *(const f16x8*)(bl0 + (size_t)(16 * i) * D + 32 * f);
      acc[i] = __builtin_amdgcn_mfma_f32_16x16x32_f16(ahi, bhi, acc[i], 0, 0, 0);
      acc[i] = __builtin_amdgcn_mfma_f32_16x16x32_f16(alo, bhi, acc[i], 0, 0, 0);
      acc[i] = __builtin_amdgcn_mfma_f32_16x16x32_f16(ahi, blo, acc[i], 0, 0, 0);
    }
  }

#pragma unroll
  for (int i = 0; i < 8; ++i) {
    const int n = n0 + 16 * i + l15;
    const float bb = bih[n];
#pragma unroll
    for (int reg = 0; reg < 4; ++reg) {
      const int m = m0 + 16 * w + 4 * lk + reg;
      gx[(size_t)m * G + n] = acc[i][reg] + bb;
    }
  }
}

// ---------------------------------------------------------------------------
// Kernel C: persistent word-GRU scan, FUSED-UPDATER + tail-fused edition.
// R5 counters: 2700 cyc/step vs 1863-cyc mfma-issue floor (96 mfma/SIMD x
// 19.4 cyc). The ~840-cyc gap was the phase structure: 2 barriers + pre[]
// LDS round-trip + dedicated-updater serial chain. Fix exploits the
// broadcast identity: A-rows all equal h => ALL D rows identical =>
// every lane's acc[j][0] IS the full dot for its column. Reassign wave w
// the gate TRIPLES for d in [32w,32w+32): tiles n = 256g + 32w + 16jj
// (g=gate, jj=0,1). After its 48 mfma, lane l15 holds aR/aZ/aN for
// d0=32w+l15 and d1=d0+16 in registers -> gate update in-reg, write 2 f16
// to hbuf, ONE lds_barrier per step. Gate VALU (1/4 lanes) overlaps the
// sibling wave's mfma on the same SIMD.
// Epilogue (same block): attn-pool over wo[b] + sentence GRU -> out[b].
// 64 WGs x 512 threads (8 waves, 2/SIMD). Bf = 6x8 f16x8 = 192 regs (AGPR).
// ---------------------------------------------------------------------------
__global__ __launch_bounds__(512, 2) void gru_scan_word(
    const float* __restrict__ gx,    // [NUTT][L][G] (includes b_ih)
    const float* __restrict__ Whh,   // [G][D]
    const float* __restrict__ bhh,   // [G]
    const float* __restrict__ uaw,   // [D]
    const float* __restrict__ sWih,  // [G][D]
    const float* __restrict__ sbih,  // [G]
    const float* __restrict__ sbhh,  // [G]
    float* __restrict__ wo,          // [NUTT][L][D]
    float* __restrict__ out) {       // [NUTT][D]
  __shared__ __align__(16) _Float16 hbuf[2][D];   // f16 h, double-buffered
  __shared__ float lg[L];
  __shared__ float red[16];
  __shared__ float part[D];
  __shared__ float ut[D];

  const int t = threadIdx.x;
  const int b = blockIdx.x;
  const int w = t >> 6;               // wave 0..7
  const int lane = t & 63;
  const int l15 = lane & 15;
  const int lk = lane >> 4;           // k-subgroup 0..3
  const int d0 = 32 * w + l15;        // this lane's dims: d0, d0+16

  // ---- Bf[2g+jj][f] = Whh[256g + 32w + 16jj + l15][32f + 8lk .. +8] ----
  f16x8 Bf[6][8];
#pragma unroll
  for (int g = 0; g < 3; ++g) {
#pragma unroll
    for (int jj = 0; jj < 2; ++jj) {
      const float* row = Whh + (size_t)(256 * g + 32 * w + 16 * jj + l15) * D + 8 * lk;
#pragma unroll
      for (int f = 0; f < 8; ++f) {
        float4 v0 = *(const float4*)(row + 32 * f);
        float4 v1 = *(const float4*)(row + 32 * f + 4);
        Bf[2 * g + jj][f] = f16x8{(_Float16)v0.x, (_Float16)v0.y,
                                  (_Float16)v0.z, (_Float16)v0.w,
                                  (_Float16)v1.x, (_Float16)v1.y,
                                  (_Float16)v1.z, (_Float16)v1.w};
      }
    }
  }

  const float bR0 = bhh[d0],       bR1 = bhh[d0 + 16];
  const float bZ0 = bhh[256 + d0], bZ1 = bhh[256 + d0 + 16];
  const float bN0 = bhh[512 + d0], bN1 = bhh[512 + d0 + 16];

  const float* gxb = gx + (size_t)b * L * G;
  float g0r = 0.f, g1r = 0.f, g0z = 0.f, g1z = 0.f, g0n = 0.f, g1n = 0.f;
  float hp0 = 0.0f, hp1 = 0.0f;
  if (lk == 0) {
    g0r = gxb[d0];       g1r = gxb[d0 + 16];
    g0z = gxb[256 + d0]; g1z = gxb[256 + d0 + 16];
    g0n = gxb[512 + d0]; g1n = gxb[512 + d0 + 16];
  }
  if (t < 256) hbuf[0][t] = (_Float16)0.0f;
  float* wob = wo + (size_t)b * L * D;
  __syncthreads();

  for (int ts = 0; ts < L; ++ts) {
    const int cur = ts & 1;
    const _Float16* hb = hbuf[cur];
    f16x8 A[8];
#pragma unroll
    for (int f = 0; f < 8; ++f)
      A[f] = *(const f16x8*)(hb + 32 * f + 8 * lk);

    float a[6];
#pragma unroll
    for (int p = 0; p < 3; ++p) {
      f32x4 accA = {0.f, 0.f, 0.f, 0.f};
      f32x4 accB = {0.f, 0.f, 0.f, 0.f};
#pragma unroll
      for (int f = 0; f < 8; ++f) {
        accA = __builtin_amdgcn_mfma_f32_16x16x32_f16(A[f], Bf[2 * p][f], accA, 0, 0, 0);
        accB = __builtin_amdgcn_mfma_f32_16x16x32_f16(A[f], Bf[2 * p + 1][f], accB, 0, 0, 0);
      }
      a[2 * p] = accA[0];          // all D rows identical (A broadcast)
      a[2 * p + 1] = accB[0];
    }

    if (lk == 0) {
      float r0 = sigm(g0r + a[0] + bR0);
      float z0 = sigm(g0z + a[2] + bZ0);
      float n0 = tanh_f(g0n + r0 * (a[4] + bN0));
      float h0 = fmaf(z0, hp0 - n0, n0);       // (1-z)*n + z*h
      float r1 = sigm(g1r + a[1] + bR1);
      float z1 = sigm(g1z + a[3] + bZ1);
      float n1 = tanh_f(g1n + r1 * (a[5] + bN1));
      float h1 = fmaf(z1, hp1 - n1, n1);
      hp0 = h0; hp1 = h1;
      _Float16* hn = hbuf[cur ^ 1];
      hn[d0] = (_Float16)h0;
      hn[d0 + 16] = (_Float16)h1;
      float* wr = wob + (size_t)ts * D;
      wr[d0] = h0;
      wr[d0 + 16] = h1;
      const int tn = (ts + 1 < L) ? ts + 1 : ts;
      const float* gxn = gxb + (size_t)tn * G;
      g0r = gxn[d0];       g1r = gxn[d0 + 16];
      g0z = gxn[256 + d0]; g1z = gxn[256 + d0 + 16];
      g0n = gxn[512 + d0]; g1n = gxn[512 + d0 + 16];
    }
    lds_barrier();
  }

  // ===== epilogue: attn-pool + sentence GRU (block-local) =====
  asm volatile("s_waitcnt vmcnt(0)" ::: "memory");   // wo stores done
  __syncthreads();

  // logits: wave w handles rows [64w, 64w+64)
  {
    const float ua0 = uaw[lane], ua1 = uaw[lane + 64];
    const float ua2 = uaw[lane + 128], ua3 = uaw[lane + 192];
    for (int r = 0; r < 64; ++r) {
      const int tt = 64 * w + r;
      const float* row = wob + (size_t)tt * D;
      float p = row[lane] * ua0 + row[lane + 64] * ua1 +
                row[lane + 128] * ua2 + row[lane + 192] * ua3;
#pragma unroll
      for (int off = 32; off; off >>= 1) p += __shfl_down(p, off);
      if (lane == 0) lg[tt] = p;               // ua_b cancels in softmax
    }
  }
  __syncthreads();

  // softmax over 512 logits (thread t owns lg[t])
  {
    float v = lg[t];
    float m = v;
#pragma unroll
    for (int off = 32; off; off >>= 1) m = fmaxf(m, __shfl_xor(m, off));
    if (lane == 0) red[w] = m;
    __syncthreads();
    m = red[0];
#pragma unroll
    for (int i = 1; i < 8; ++i) m = fmaxf(m, red[i]);
    float e = __expf(v - m);
    float s = e;
#pragma unroll
    for (int off = 32; off; off >>= 1) s += __shfl_xor(s, off);
    if (lane == 0) red[8 + w] = s;
    __syncthreads();
    s = red[8];
#pragma unroll
    for (int i = 9; i < 16; ++i) s += red[i];
    lg[t] = e * (1.0f / s);
  }
  __syncthreads();

  // weighted sum: half 0 sums t in [0,256), half 1 sums [256,512)
  {
    const int d = t & 255, half = t >> 8;
    float acc = 0.0f;
    const float* bb = wob + (size_t)half * 256 * D;
    const float* lgh = lg + half * 256;
#pragma unroll 4
    for (int k = 0; k < 256; ++k)
      acc = fmaf(lgh[k], bb[(size_t)k * D + d], acc);
    if (half == 1) part[d] = acc;
    __syncthreads();
    if (half == 0) ut[d] = acc + part[d];
    __syncthreads();
  }

  // sentence GRU (T=1, h0=0) -> out = (1-z)*n
  if (t < 256) {
    const int d = t;
    const float* wr = sWih + (size_t)d * D;
    const float* wz = sWih + (size_t)(D + d) * D;
    const float* wn = sWih + (size_t)(2 * D + d) * D;
    float ar = 0.0f, az = 0.0f, an = 0.0f;
    for (int k = 0; k < D; k += 4) {
      float4 vr = *(const float4*)(wr + k);
      float4 vz = *(const float4*)(wz + k);
      float4 vn = *(const float4*)(wn + k);
      float u0 = ut[k], u1 = ut[k + 1], u2 = ut[k + 2], u3 = ut[k + 3];
      ar += vr.x * u0 + vr.y * u1 + vr.z * u2 + vr.w * u3;
      az += vz.x * u0 + vz.y * u1 + vz.z * u2 + vz.w * u3;
      an += vn.x * u0 + vn.y * u1 + vn.z * u2 + vn.w * u3;
    }
    float r = sigm(ar + sbih[d] + sbhh[d]);
    float z = sigm(az + sbih[D + d] + sbhh[D + d]);
    float n = tanh_f(an + sbih[2 * D + d] + r * sbhh[2 * D + d]);
    out[(size_t)b * D + d] = (1.0f - z) * n;
  }
}

// ---------------------------------------------------------------------------
extern "C" void kernel_launch(void* const* d_in, const int* in_sizes, int n_in,
                              void* d_out, int out_size, void* d_ws, size_t ws_size,
                              hipStream_t stream) {
  const int* tokens    = (const int*)d_in[0];
  const float* embed   = (const float*)d_in[1];
  const float* wg_Wih  = (const float*)d_in[2];
  const float* wg_Whh  = (const float*)d_in[3];
  const float* wg_bih  = (const float*)d_in[4];
  const float* wg_bhh  = (const float*)d_in[5];
  const float* ua_w    = (const float*)d_in[6];
  // d_in[7] ua_b: softmax shift-invariant -> unused
  const float* sg_Wih  = (const float*)d_in[8];
  // d_in[9] sg_Whh: h0 == 0 -> unused
  const float* sg_bih  = (const float*)d_in[10];
  const float* sg_bhh  = (const float*)d_in[11];
  // d_in[12..13] da_w/da_b: softmax over T=1 -> unused
  float* out = (float*)d_out;

  char* ws = (char*)d_ws;
  float* gx  = (float*)ws;                                     // 96 MB
  char* wo_region = ws + (size_t)NUTT * L * G * 4;
  float* wo  = (float*)wo_region;                              // 32 MB

  // Wih f16 hi/lo split lives at the head of the wo region: it is consumed
  // by gx_gemm_mfma BEFORE gru_scan_word overwrites wo (same stream, ordered).
  _Float16* whi = (_Float16*)wo_region;
  _Float16* wlo = whi + (size_t)G * D;                         // 2 x 384 KB

  split_wih<<<G, 256, 0, stream>>>(wg_Wih, whi, wlo);
  dim3 gB(512, 6);
  gx_gemm_mfma<<<gB, 256, 0, stream>>>(tokens, embed, whi, wlo, wg_bih, gx);
  gru_scan_word<<<NUTT, 512, 0, stream>>>(gx, wg_Whh, wg_bhh, ua_w,
                                          sg_Wih, sg_bih, sg_bhh, wo, out);
}

// Round 7
// 820.664 us; speedup vs baseline: 2.1626x; 2.1626x over previous
//
#include <hip/hip_runtime.h>

typedef _Float16 f16x8 __attribute__((ext_vector_type(8)));
typedef float f32x4 __attribute__((ext_vector_type(4)));

constexpr int D = 256;
constexpr int NUTT = 64;
constexpr int L = 512;
constexpr int G = 768;           // 3*D

// LDS-only barrier: orders ds_* ops across the workgroup WITHOUT draining
// vmcnt — global prefetch loads / wo stores stay in flight across steps.
__device__ __forceinline__ void lds_barrier() {
  asm volatile("s_waitcnt lgkmcnt(0)\n\ts_barrier" ::: "memory");
}

__device__ __forceinline__ float fast_rcp(float x) {
  return __builtin_amdgcn_rcpf(x);
}
__device__ __forceinline__ float sigm(float x) {
  return fast_rcp(1.0f + __expf(-x));
}
__device__ __forceinline__ float tanh_f(float x) {
  float ax = fabsf(x);
  float e = __expf(-2.0f * ax);
  float r = (1.0f - e) * fast_rcp(1.0f + e);
  return copysignf(r, x);
}

// ---------------------------------------------------------------------------
// Kernel A: split Wih (f32) -> f16 hi/lo, PRE-PACKED in MFMA fragment order.
// R5 diagnosis: the gemm's B-loads were 16 scattered 16B reads per
// quarter-wave (512B row stride). Packed layout makes each wave's
// (tile,f) B-load one contiguous 1KB stream:
//   pk[(((it*8+f)*4+lk)*16+l15)*8+j] = f16(W[16it+l15][32f+8lk+j])
// ---------------------------------------------------------------------------
__global__ __launch_bounds__(256) void pack_wih(
    const float* __restrict__ Wih, _Float16* __restrict__ hi,
    _Float16* __restrict__ lo) {
  const int e = blockIdx.x * 256 + threadIdx.x;    // grid = 768 blocks
  const int g = e >> 8, k = e & 255;
  float v = Wih[e];
  _Float16 h = (_Float16)v;
  _Float16 l = (_Float16)(v - (float)h);
  const int it = g >> 4, l15 = g & 15;
  const int f = k >> 5, r = k & 31, lk = r >> 3, j = r & 7;
  const int dst = ((((it * 8 + f) * 4 + lk) * 16 + l15) * 8) + j;
  hi[dst] = h;
  lo[dst] = l;
}

// ---------------------------------------------------------------------------
// Kernel B: gx[m][g] = embed[tokens[m]][:] . Wih[g][:] + bih[g]
// MFMA split-f16, packed-B edition. M=32768, N=768, K=256.
// BM=64 (4 waves x 16 rows), BN=128 (8 16-col tiles).
// A fragment: 32B of the lane's token row direct from embed (L3-resident).
// B fragment: one coalesced f16x8 from the packed stream per (tile,f).
// 3 mfma per (tile,f): Ahi*Bhi + Alo*Bhi + Ahi*Blo (f32 accum).
// ---------------------------------------------------------------------------
__global__ __launch_bounds__(256) void gx_gemm_mfma(
    const int* __restrict__ tokens, const float* __restrict__ embed,
    const _Float16* __restrict__ whi, const _Float16* __restrict__ wlo,
    const float* __restrict__ bih, float* __restrict__ gx) {
  const int tid = threadIdx.x;
  const int m0 = blockIdx.x * 64;
  const int n0 = blockIdx.y * 128;
  const int it0 = blockIdx.y * 8;        // first 16-col tile index

  const int w = tid >> 6;                // wave 0..3
  const int lane = tid & 63;
  const int l15 = lane & 15;
  const int lk = lane >> 4;

  const int tok = tokens[m0 + 16 * w + l15];
  const float* arow = embed + (size_t)tok * D;

  const f16x8* Bh = (const f16x8*)whi;
  const f16x8* Bl = (const f16x8*)wlo;
  const int fragbase = lk * 16 + l15;    // + (it*8+f)*64

  f32x4 acc[8] = {};

#pragma unroll
  for (int f = 0; f < 8; ++f) {
    // A fragment: 32B of this lane's row, f32 -> (hi, lo) f16x8
    const float* ap = arow + 32 * f + 8 * lk;
    float4 v0 = *(const float4*)(ap);
    float4 v1 = *(const float4*)(ap + 4);
    float av[8] = {v0.x, v0.y, v0.z, v0.w, v1.x, v1.y, v1.z, v1.w};
    f16x8 ahi, alo;
#pragma unroll
    for (int j = 0; j < 8; ++j) {
      _Float16 h = (_Float16)av[j];
      ahi[j] = h;
      alo[j] = (_Float16)(av[j] - (float)h);
    }
#pragma unroll
    for (int i = 0; i < 8; ++i) {
      const int frag = ((it0 + i) * 8 + f) * 64 + fragbase;
      f16x8 bhi = Bh[frag];
      f16x8 blo = Bl[frag];
      acc[i] = __builtin_amdgcn_mfma_f32_16x16x32_f16(ahi, bhi, acc[i], 0, 0, 0);
      acc[i] = __builtin_amdgcn_mfma_f32_16x16x32_f16(alo, bhi, acc[i], 0, 0, 0);
      acc[i] = __builtin_amdgcn_mfma_f32_16x16x32_f16(ahi, blo, acc[i], 0, 0, 0);
    }
  }

  // epilogue: D row = 4*lk + reg (within wave's 16-row strip), col = l15
#pragma unroll
  for (int i = 0; i < 8; ++i) {
    const int n = n0 + 16 * i + l15;
    const float bb = bih[n];
#pragma unroll
    for (int reg = 0; reg < 4; ++reg) {
      const int m = m0 + 16 * w + 4 * lk + reg;
      gx[(size_t)m * G + n] = acc[i][reg] + bb;
    }
  }
}

// ---------------------------------------------------------------------------
// Kernel C: persistent word-GRU scan — R5-verified 2-phase loop (577 µs)
// + fused attn-pool/sentence-GRU epilogue (R6-verified correct, loop
// restructure from R6 reverted: exec-masked in-wave gates + 1 barrier
// globally serialized the gate chain -> 2.6x regression).
// 64 WGs x 512 threads (8 waves, 2/SIMD). Wave w owns cols [96w, 96w+96):
// 6 16-col tiles; Bf = 6x8 f16x8 = 192 regs (AGPR), loop-invariant.
// Phase 1: 48 mfma/wave -> lk==0 lanes publish acc[0] to pre[3][D] (SoA,
// conflict-free). Phase 2: threads t<256 do the gate update (coalesced gx
// prefetch + wo store). Two LDS-only barriers per step.
// ---------------------------------------------------------------------------
__global__ __launch_bounds__(512, 2) void gru_scan_word(
    const float* __restrict__ gx,    // [NUTT][L][G] (includes b_ih)
    const float* __restrict__ Whh,   // [G][D]
    const float* __restrict__ bhh,   // [G]
    const float* __restrict__ uaw,   // [D]
    const float* __restrict__ sWih,  // [G][D]
    const float* __restrict__ sbih,  // [G]
    const float* __restrict__ sbhh,  // [G]
    float* __restrict__ wo,          // [NUTT][L][D]
    float* __restrict__ out) {       // [NUTT][D]
  __shared__ __align__(16) _Float16 hbuf[2][D];   // f16 h, double-buffered
  __shared__ float pre[3][D];                     // [comp][d] = aR/aZ/aN
  __shared__ float lg[L];
  __shared__ float red[16];
  __shared__ float part[D];
  __shared__ float ut[D];

  const int t = threadIdx.x;          // updater: t < 256, d = t
  const int b = blockIdx.x;
  const int w = t >> 6;               // wave 0..7
  const int lane = t & 63;
  const int l15 = lane & 15;          // B col / D col within tile
  const int lk = lane >> 4;           // k-subgroup 0..3

  // ---- preload B fragments: Bf[i][f][j] = Whh[n][32f + 8lk + j], f16 ----
  f16x8 Bf[6][8];
#pragma unroll
  for (int i = 0; i < 6; ++i) {
    const float* row = Whh + (size_t)(96 * w + 16 * i + l15) * D + 8 * lk;
#pragma unroll
    for (int f = 0; f < 8; ++f) {
      float4 v0 = *(const float4*)(row + 32 * f);
      float4 v1 = *(const float4*)(row + 32 * f + 4);
      Bf[i][f] = f16x8{(_Float16)v0.x, (_Float16)v0.y,
                       (_Float16)v0.z, (_Float16)v0.w,
                       (_Float16)v1.x, (_Float16)v1.y,
                       (_Float16)v1.z, (_Float16)v1.w};
    }
  }

  float bR = 0.0f, bZ = 0.0f, bN = 0.0f;
  float gr = 0.0f, gz = 0.0f, gn = 0.0f;
  const float* gxb = gx + (size_t)b * L * G;
  if (t < 256) {
    bR = bhh[t]; bZ = bhh[D + t]; bN = bhh[2 * D + t];
    gr = gxb[t]; gz = gxb[D + t]; gn = gxb[2 * D + t];
    hbuf[0][t] = (_Float16)0.0f;
  }
  float hprev = 0.0f;
  float* wob = wo + (size_t)b * L * D;
  __syncthreads();

  for (int ts = 0; ts < L; ++ts) {
    const int cur = ts & 1;

    // A fragments: broadcast h (identical within each 16-lane k-group)
    const _Float16* hb = hbuf[cur];
    f16x8 A[8];
#pragma unroll
    for (int f = 0; f < 8; ++f)
      A[f] = *(const f16x8*)(hb + 32 * f + 8 * lk);

#pragma unroll
    for (int i = 0; i < 6; ++i) {
      f32x4 acc = {0.0f, 0.0f, 0.0f, 0.0f};
#pragma unroll
      for (int f = 0; f < 8; ++f)
        acc = __builtin_amdgcn_mfma_f32_16x16x32_f16(A[f], Bf[i][f], acc,
                                                     0, 0, 0);
      if (lk == 0) {                    // all D rows equal; lanes 0-15 write
        const int n = 96 * w + 16 * i + l15;
        pre[n >> 8][n & 255] = acc[0];
      }
    }
    lds_barrier();

    if (t < 256) {
      float aR = pre[0][t], aZ = pre[1][t], aN = pre[2][t];
      float r = sigm(gr + aR + bR);
      float z = sigm(gz + aZ + bZ);
      float nn = tanh_f(gn + r * (aN + bN));
      float hn = fmaf(z, hprev - nn, nn);    // (1-z)*n + z*h
      hprev = hn;
      hbuf[cur ^ 1][t] = (_Float16)hn;
      wob[(size_t)ts * D + t] = hn;
      const int tn = (ts + 1 < L) ? ts + 1 : ts;
      const float* gxn = gxb + (size_t)tn * G;
      gr = gxn[t]; gz = gxn[D + t]; gn = gxn[2 * D + t];
    }
    lds_barrier();
  }

  // ===== epilogue: attn-pool + sentence GRU (block-local) =====
  asm volatile("s_waitcnt vmcnt(0)" ::: "memory");   // wo stores done
  __syncthreads();

  // logits: wave w handles rows [64w, 64w+64)
  {
    const float ua0 = uaw[lane], ua1 = uaw[lane + 64];
    const float ua2 = uaw[lane + 128], ua3 = uaw[lane + 192];
    for (int r = 0; r < 64; ++r) {
      const int tt = 64 * w + r;
      const float* row = wob + (size_t)tt * D;
      float p = row[lane] * ua0 + row[lane + 64] * ua1 +
                row[lane + 128] * ua2 + row[lane + 192] * ua3;
#pragma unroll
      for (int off = 32; off; off >>= 1) p += __shfl_down(p, off);
      if (lane == 0) lg[tt] = p;               // ua_b cancels in softmax
    }
  }
  __syncthreads();

  // softmax over 512 logits (thread t owns lg[t])
  {
    float v = lg[t];
    float m = v;
#pragma unroll
    for (int off = 32; off; off >>= 1) m = fmaxf(m, __shfl_xor(m, off));
    if (lane == 0) red[w] = m;
    __syncthreads();
    m = red[0];
#pragma unroll
    for (int i = 1; i < 8; ++i) m = fmaxf(m, red[i]);
    float e = __expf(v - m);
    float s = e;
#pragma unroll
    for (int off = 32; off; off >>= 1) s += __shfl_xor(s, off);
    if (lane == 0) red[8 + w] = s;
    __syncthreads();
    s = red[8];
#pragma unroll
    for (int i = 9; i < 16; ++i) s += red[i];
    lg[t] = e * (1.0f / s);
  }
  __syncthreads();

  // weighted sum: half 0 sums t in [0,256), half 1 sums [256,512)
  {
    const int d = t & 255, half = t >> 8;
    float acc = 0.0f;
    const float* bb = wob + (size_t)half * 256 * D;
    const float* lgh = lg + half * 256;
#pragma unroll 4
    for (int k = 0; k < 256; ++k)
      acc = fmaf(lgh[k], bb[(size_t)k * D + d], acc);
    if (half == 1) part[d] = acc;
    __syncthreads();
    if (half == 0) ut[d] = acc + part[d];
    __syncthreads();
  }

  // sentence GRU (T=1, h0=0) -> out = (1-z)*n
  if (t < 256) {
    const int d = t;
    const float* wr = sWih + (size_t)d * D;
    const float* wz = sWih + (size_t)(D + d) * D;
    const float* wn = sWih + (size_t)(2 * D + d) * D;
    float ar = 0.0f, az = 0.0f, an = 0.0f;
    for (int k = 0; k < D; k += 4) {
      float4 vr = *(const float4*)(wr + k);
      float4 vz = *(const float4*)(wz + k);
      float4 vn = *(const float4*)(wn + k);
      float u0 = ut[k], u1 = ut[k + 1], u2 = ut[k + 2], u3 = ut[k + 3];
      ar += vr.x * u0 + vr.y * u1 + vr.z * u2 + vr.w * u3;
      az += vz.x * u0 + vz.y * u1 + vz.z * u2 + vz.w * u3;
      an += vn.x * u0 + vn.y * u1 + vn.z * u2 + vn.w * u3;
    }
    float r = sigm(ar + sbih[d] + sbhh[d]);
    float z = sigm(az + sbih[D + d] + sbhh[D + d]);
    float n = tanh_f(an + sbih[2 * D + d] + r * sbhh[2 * D + d]);
    out[(size_t)b * D + d] = (1.0f - z) * n;
  }
}

// ---------------------------------------------------------------------------
extern "C" void kernel_launch(void* const* d_in, const int* in_sizes, int n_in,
                              void* d_out, int out_size, void* d_ws, size_t ws_size,
                              hipStream_t stream) {
  const int* tokens    = (const int*)d_in[0];
  const float* embed   = (const float*)d_in[1];
  const float* wg_Wih  = (const float*)d_in[2];
  const float* wg_Whh  = (const float*)d_in[3];
  const float* wg_bih  = (const float*)d_in[4];
  const float* wg_bhh  = (const float*)d_in[5];
  const float* ua_w    = (const float*)d_in[6];
  // d_in[7] ua_b: softmax shift-invariant -> unused
  const float* sg_Wih  = (const float*)d_in[8];
  // d_in[9] sg_Whh: h0 == 0 -> unused
  const float* sg_bih  = (const float*)d_in[10];
  const float* sg_bhh  = (const float*)d_in[11];
  // d_in[12..13] da_w/da_b: softmax over T=1 -> unused
  float* out = (float*)d_out;

  char* ws = (char*)d_ws;
  float* gx  = (float*)ws;                                     // 96 MB
  char* wo_region = ws + (size_t)NUTT * L * G * 4;
  float* wo  = (float*)wo_region;                              // 32 MB

  // packed Wih f16 hi/lo lives at the head of the wo region: consumed by
  // gx_gemm_mfma BEFORE gru_scan_word overwrites wo (same stream, ordered).
  _Float16* whi = (_Float16*)wo_region;
  _Float16* wlo = whi + (size_t)G * D;                         // 2 x 384 KB

  pack_wih<<<G, 256, 0, stream>>>(wg_Wih, whi, wlo);
  dim3 gB(512, 6);
  gx_gemm_mfma<<<gB, 256, 0, stream>>>(tokens, embed, whi, wlo, wg_bih, gx);
  gru_scan_word<<<NUTT, 512, 0, stream>>>(gx, wg_Whh, wg_bhh, ua_w,
                                          sg_Wih, sg_bih, sg_bhh, wo, out);
}

// Round 8
// 784.031 us; speedup vs baseline: 2.2637x; 1.0467x over previous
//
#include <hip/hip_runtime.h>

typedef _Float16 f16x8 __attribute__((ext_vector_type(8)));
typedef float f32x4 __attribute__((ext_vector_type(4)));

constexpr int D = 256;
constexpr int NUTT = 64;
constexpr int L = 512;
constexpr int G = 768;           // 3*D
constexpr int CHUNK = 128;       // timesteps per producer chunk
constexpr int NCH = L / CHUNK;   // 4 chunks per utterance
constexpr int NBLK = 6;          // 128-col n-blocks over G=768
constexpr int NGEMM = NCH * NUTT * NBLK;   // 1536 producer blocks

// LDS-only barrier: orders ds_* ops across the workgroup WITHOUT draining
// vmcnt — global prefetch loads / h stores stay in flight across steps.
__device__ __forceinline__ void lds_barrier() {
  asm volatile("s_waitcnt lgkmcnt(0)\n\ts_barrier" ::: "memory");
}

__device__ __forceinline__ float fast_rcp(float x) {
  return __builtin_amdgcn_rcpf(x);
}
__device__ __forceinline__ float sigm(float x) {
  return fast_rcp(1.0f + __expf(-x));
}
__device__ __forceinline__ float tanh_f(float x) {
  float ax = fabsf(x);
  float e = __expf(-2.0f * ax);
  float r = (1.0f - e) * fast_rcp(1.0f + e);
  return copysignf(r, x);
}

// ---------------------------------------------------------------------------
// Kernel A: pack Wih (f32) -> f16 hi/lo in MFMA fragment order (R7-verified)
//   pk[(((it*8+f)*4+lk)*16+l15)*8+j] = f16(W[16it+l15][32f+8lk+j])
// Block 0 also zeroes the producer-consumer flags (64B-padded, 256 entries).
// ---------------------------------------------------------------------------
__global__ __launch_bounds__(256) void pack_wih(
    const float* __restrict__ Wih, _Float16* __restrict__ hi,
    _Float16* __restrict__ lo, int* cnt) {
  if (blockIdx.x == 0) cnt[threadIdx.x << 4] = 0;
  const int e = blockIdx.x * 256 + threadIdx.x;    // grid = 768 blocks
  const int g = e >> 8, k = e & 255;
  float v = Wih[e];
  _Float16 h = (_Float16)v;
  _Float16 l = (_Float16)(v - (float)h);
  const int it = g >> 4, l15 = g & 15;
  const int f = k >> 5, r = k & 31, lk = r >> 3, j = r & 7;
  const int dst = ((((it * 8 + f) * 4 + lk) * 16 + l15) * 8) + j;
  hi[dst] = h;
  lo[dst] = l;
}

// ---------------------------------------------------------------------------
// Mega-kernel: blocks [0,64) = persistent gru consumers (1 per utterance),
// blocks [64, 64+1536) = gemm producers in CHUNK-MAJOR order so every
// utterance's chunk 0 is produced first (~25 µs on the idle CUs), then the
// 8x-faster producer wave stays ahead of the 640 µs consumer scan.
// Handshake per (utt,chunk): producers release-increment a padded flag after
// __syncthreads() (drains vmcnt); consumer t0 acquire-spins to 6.
// Producers never wait -> no deadlock under any dispatch order.
// wo buffer ELIMINATED: h(ts) is stored into gx[b][ts][0:256], which the
// updater freed one step earlier (prefetch of ts happens at step ts-1);
// the fused attn-pool epilogue reads rows at stride G.
// ---------------------------------------------------------------------------
__global__ __launch_bounds__(512, 2) void hran_mega(
    const int* __restrict__ tokens, const float* __restrict__ embed,
    const _Float16* __restrict__ whi, const _Float16* __restrict__ wlo,
    const float* __restrict__ bih,   // wg_bih
    const float* __restrict__ Whh,   // wg_Whh
    const float* __restrict__ bhh,   // wg_bhh
    const float* __restrict__ uaw,   // ua_w
    const float* __restrict__ sWih, const float* __restrict__ sbih,
    const float* __restrict__ sbhh,
    float* __restrict__ gx,          // [NUTT][L][G]; cols 0:256 reused for h
    int* cnt,                        // 256 flags, 64B-padded
    float* __restrict__ out) {       // [NUTT][D]
  __shared__ __align__(16) _Float16 hbuf[2][D];
  __shared__ float pre[3][D];
  __shared__ float lg[L];
  __shared__ float red[16];
  __shared__ float part[D];
  __shared__ float ut[D];

  const int bx = blockIdx.x;
  const int t = threadIdx.x;
  const int w = t >> 6;               // wave 0..7
  const int lane = t & 63;
  const int l15 = lane & 15;
  const int lk = lane >> 4;

  if (bx >= NUTT) {
    // =================== gemm producer role (R7-verified math) ===========
    const int gbx = bx - NUTT;
    const int c = gbx / (NUTT * NBLK);         // chunk-major
    const int rem = gbx % (NUTT * NBLK);
    const int u = rem / NBLK;
    const int nb = rem % NBLK;
    const int m0 = u * L + c * CHUNK;          // 128 rows (8 waves x 16)
    const int n0 = nb * 128;
    const int it0 = nb * 8;

    const int tok = tokens[m0 + 16 * w + l15];
    const float* arow = embed + (size_t)tok * D;
    const f16x8* Bh = (const f16x8*)whi;
    const f16x8* Bl = (const f16x8*)wlo;
    const int fragbase = lk * 16 + l15;

    f32x4 acc[8] = {};
#pragma unroll
    for (int f = 0; f < 8; ++f) {
      const float* ap = arow + 32 * f + 8 * lk;
      float4 v0 = *(const float4*)(ap);
      float4 v1 = *(const float4*)(ap + 4);
      float av[8] = {v0.x, v0.y, v0.z, v0.w, v1.x, v1.y, v1.z, v1.w};
      f16x8 ahi, alo;
#pragma unroll
      for (int j = 0; j < 8; ++j) {
        _Float16 h = (_Float16)av[j];
        ahi[j] = h;
        alo[j] = (_Float16)(av[j] - (float)h);
      }
#pragma unroll
      for (int i = 0; i < 8; ++i) {
        const int frag = ((it0 + i) * 8 + f) * 64 + fragbase;
        f16x8 bhi = Bh[frag];
        f16x8 blo = Bl[frag];
        acc[i] = __builtin_amdgcn_mfma_f32_16x16x32_f16(ahi, bhi, acc[i], 0, 0, 0);
        acc[i] = __builtin_amdgcn_mfma_f32_16x16x32_f16(alo, bhi, acc[i], 0, 0, 0);
        acc[i] = __builtin_amdgcn_mfma_f32_16x16x32_f16(ahi, blo, acc[i], 0, 0, 0);
      }
    }
#pragma unroll
    for (int i = 0; i < 8; ++i) {
      const int n = n0 + 16 * i + l15;
      const float bb = bih[n];
#pragma unroll
      for (int reg = 0; reg < 4; ++reg) {
        const int m = m0 + 16 * w + 4 * lk + reg;
        gx[(size_t)m * G + n] = acc[i][reg] + bb;
      }
    }
    __syncthreads();                 // drains vmcnt: all stores issued
    if (t == 0)
      __hip_atomic_fetch_add(&cnt[((u << 2) + c) << 4], 1,
                             __ATOMIC_RELEASE, __HIP_MEMORY_SCOPE_AGENT);
    return;
  }

  // ====================== gru consumer role ==============================
  const int b = bx;

  // ---- Bf[i][f][j] = Whh[96w + 16i + l15][32f + 8lk + j], f16 ----
  f16x8 Bf[6][8];
#pragma unroll
  for (int i = 0; i < 6; ++i) {
    const float* row = Whh + (size_t)(96 * w + 16 * i + l15) * D + 8 * lk;
#pragma unroll
    for (int f = 0; f < 8; ++f) {
      float4 v0 = *(const float4*)(row + 32 * f);
      float4 v1 = *(const float4*)(row + 32 * f + 4);
      Bf[i][f] = f16x8{(_Float16)v0.x, (_Float16)v0.y,
                       (_Float16)v0.z, (_Float16)v0.w,
                       (_Float16)v1.x, (_Float16)v1.y,
                       (_Float16)v1.z, (_Float16)v1.w};
    }
  }

  float bR = 0.0f, bZ = 0.0f, bN = 0.0f;
  float gr = 0.0f, gz = 0.0f, gn = 0.0f;
  float hprev = 0.0f;
  float* gxb = gx + (size_t)b * L * G;
  if (t < 256) {
    bR = bhh[t]; bZ = bhh[D + t]; bN = bhh[2 * D + t];
    hbuf[0][t] = (_Float16)0.0f;
  }
  __syncthreads();

  for (int c = 0; c < NCH; ++c) {
    // wait for this utterance's chunk c (6 producer blocks)
    if (t == 0) {
      while (__hip_atomic_load(&cnt[((b << 2) + c) << 4],
                               __ATOMIC_ACQUIRE,
                               __HIP_MEMORY_SCOPE_AGENT) < NBLK)
        __builtin_amdgcn_s_sleep(8);
    }
    __syncthreads();
    __threadfence();
    if (t < 256) {                   // chunk-entry g* load (deferred prefetch)
      const float* gc = gxb + (size_t)(CHUNK * c) * G;
      gr = gc[t]; gz = gc[D + t]; gn = gc[2 * D + t];
    }

    for (int tsl = 0; tsl < CHUNK; ++tsl) {
      const int ts = CHUNK * c + tsl;
      const int cur = ts & 1;
      const _Float16* hb = hbuf[cur];
      f16x8 A[8];
#pragma unroll
      for (int f = 0; f < 8; ++f)
        A[f] = *(const f16x8*)(hb + 32 * f + 8 * lk);

#pragma unroll
      for (int i = 0; i < 6; ++i) {
        f32x4 acc = {0.0f, 0.0f, 0.0f, 0.0f};
#pragma unroll
        for (int f = 0; f < 8; ++f)
          acc = __builtin_amdgcn_mfma_f32_16x16x32_f16(A[f], Bf[i][f], acc,
                                                       0, 0, 0);
        if (lk == 0) {                // all D rows equal; lanes 0-15 publish
          const int n = 96 * w + 16 * i + l15;
          pre[n >> 8][n & 255] = acc[0];
        }
      }
      lds_barrier();

      if (t < 256) {
        float aR = pre[0][t], aZ = pre[1][t], aN = pre[2][t];
        float r = sigm(gr + aR + bR);
        float z = sigm(gz + aZ + bZ);
        float nn = tanh_f(gn + r * (aN + bN));
        float hn = fmaf(z, hprev - nn, nn);    // (1-z)*n + z*h
        hprev = hn;
        hbuf[cur ^ 1][t] = (_Float16)hn;
        gxb[(size_t)ts * G + t] = hn;          // h into freed gx slot
        const int tn = ts + 1;
        if (tn & (CHUNK - 1)) {                // within chunk: prefetch
          const float* gxn = gxb + (size_t)tn * G;
          gr = gxn[t]; gz = gxn[D + t]; gn = gxn[2 * D + t];
        }
      }
      lds_barrier();
    }
  }

  // ===== fused epilogue: attn-pool + sentence GRU (block-local) =====
  asm volatile("s_waitcnt vmcnt(0)" ::: "memory");   // h stores done
  __syncthreads();

  // logits: wave w handles rows [64w, 64w+64); h rows live at stride G
  {
    const float ua0 = uaw[lane], ua1 = uaw[lane + 64];
    const float ua2 = uaw[lane + 128], ua3 = uaw[lane + 192];
    for (int r = 0; r < 64; ++r) {
      const int tt = 64 * w + r;
      const float* row = gxb + (size_t)tt * G;
      float p = row[lane] * ua0 + row[lane + 64] * ua1 +
                row[lane + 128] * ua2 + row[lane + 192] * ua3;
#pragma unroll
      for (int off = 32; off; off >>= 1) p += __shfl_down(p, off);
      if (lane == 0) lg[tt] = p;               // ua_b cancels in softmax
    }
  }
  __syncthreads();

  // softmax over 512 logits (thread t owns lg[t])
  {
    float v = lg[t];
    float m = v;
#pragma unroll
    for (int off = 32; off; off >>= 1) m = fmaxf(m, __shfl_xor(m, off));
    if (lane == 0) red[w] = m;
    __syncthreads();
    m = red[0];
#pragma unroll
    for (int i = 1; i < 8; ++i) m = fmaxf(m, red[i]);
    float e = __expf(v - m);
    float s = e;
#pragma unroll
    for (int off = 32; off; off >>= 1) s += __shfl_xor(s, off);
    if (lane == 0) red[8 + w] = s;
    __syncthreads();
    s = red[8];
#pragma unroll
    for (int i = 9; i < 16; ++i) s += red[i];
    lg[t] = e * (1.0f / s);
  }
  __syncthreads();

  // weighted sum: half 0 sums ts in [0,256), half 1 sums [256,512)
  {
    const int d = t & 255, half = t >> 8;
    float acc = 0.0f;
    const float* bb = gxb + (size_t)half * 256 * G;
    const float* lgh = lg + half * 256;
#pragma unroll 4
    for (int k = 0; k < 256; ++k)
      acc = fmaf(lgh[k], bb[(size_t)k * G + d], acc);
    if (half == 1) part[d] = acc;
    __syncthreads();
    if (half == 0) ut[d] = acc + part[d];
    __syncthreads();
  }

  // sentence GRU (T=1, h0=0) -> out = (1-z)*n
  if (t < 256) {
    const int d = t;
    const float* wr = sWih + (size_t)d * D;
    const float* wz = sWih + (size_t)(D + d) * D;
    const float* wn = sWih + (size_t)(2 * D + d) * D;
    float ar = 0.0f, az = 0.0f, an = 0.0f;
    for (int k = 0; k < D; k += 4) {
      float4 vr = *(const float4*)(wr + k);
      float4 vz = *(const float4*)(wz + k);
      float4 vn = *(const float4*)(wn + k);
      float u0 = ut[k], u1 = ut[k + 1], u2 = ut[k + 2], u3 = ut[k + 3];
      ar += vr.x * u0 + vr.y * u1 + vr.z * u2 + vr.w * u3;
      az += vz.x * u0 + vz.y * u1 + vz.z * u2 + vz.w * u3;
      an += vn.x * u0 + vn.y * u1 + vn.z * u2 + vn.w * u3;
    }
    float r = sigm(ar + sbih[d] + sbhh[d]);
    float z = sigm(az + sbih[D + d] + sbhh[D + d]);
    float n = tanh_f(an + sbih[2 * D + d] + r * sbhh[2 * D + d]);
    out[(size_t)b * D + d] = (1.0f - z) * n;
  }
}

// ---------------------------------------------------------------------------
extern "C" void kernel_launch(void* const* d_in, const int* in_sizes, int n_in,
                              void* d_out, int out_size, void* d_ws, size_t ws_size,
                              hipStream_t stream) {
  const int* tokens    = (const int*)d_in[0];
  const float* embed   = (const float*)d_in[1];
  const float* wg_Wih  = (const float*)d_in[2];
  const float* wg_Whh  = (const float*)d_in[3];
  const float* wg_bih  = (const float*)d_in[4];
  const float* wg_bhh  = (const float*)d_in[5];
  const float* ua_w    = (const float*)d_in[6];
  // d_in[7] ua_b: softmax shift-invariant -> unused
  const float* sg_Wih  = (const float*)d_in[8];
  // d_in[9] sg_Whh: h0 == 0 -> unused
  const float* sg_bih  = (const float*)d_in[10];
  const float* sg_bhh  = (const float*)d_in[11];
  // d_in[12..13] da_w/da_b: softmax over T=1 -> unused
  float* out = (float*)d_out;

  char* ws = (char*)d_ws;
  const size_t GXB = (size_t)NUTT * L * G * 4;                 // 96 MB
  float* gx = (float*)ws;                                      // + h in-place
  _Float16* whi = (_Float16*)(ws + GXB);                       // 384 KB
  _Float16* wlo = whi + (size_t)G * D;                         // 384 KB
  int* cnt = (int*)(ws + GXB + (size_t)2 * G * D * 2);         // 16 KB flags

  pack_wih<<<G, 256, 0, stream>>>(wg_Wih, whi, wlo, cnt);
  hran_mega<<<NUTT + NGEMM, 512, 0, stream>>>(
      tokens, embed, whi, wlo, wg_bih, wg_Whh, wg_bhh, ua_w,
      sg_Wih, sg_bih, sg_bhh, gx, cnt, out);
}